// Round 2
// baseline (218.647 us; speedup 1.0000x reference)
//
#include <hip/hip_runtime.h>
#include <hip/hip_bf16.h>

typedef __bf16 bf16;
typedef __bf16 bf16x8 __attribute__((ext_vector_type(8)));
typedef float f32x4 __attribute__((ext_vector_type(4)));

#define BB 64
#define EMB 256
#define UNITS 512
#define POI 5000
#define KCAT 1280
#define SCLD 5024   // sc row stride (5000 padded to x32)
#define L2E 1.4426950408889634f

__device__ __forceinline__ float rcp_(float x){ return __builtin_amdgcn_rcpf(x); }
__device__ __forceinline__ float exp2_(float x){ return __builtin_amdgcn_exp2f(x); }

// ---- one 16x16x(K) MFMA C-tile from fp32 sources, on-the-fly bf16 cvt.
// ap: per-row A pointer (row-major, contiguous K). B fp32 row-major [K, ldb]: lane -> B[q*8+j][nc].
// C/D: col=lane&15, row=q*4+reg (m89-verified).
__device__ __forceinline__ f32x4 mm16r(const float* __restrict__ ap, const float* __restrict__ B,
                                       int ldb, int K, int nc, int lane){
  int q = lane >> 4;
  f32x4 acc = {0.f,0.f,0.f,0.f};
  ap += q*8;
  const float* bp = B + (size_t)(q*8)*ldb + nc;
#pragma unroll 2
  for(int k0 = 0; k0 < K; k0 += 32){
    f32x4 a0 = *(const f32x4*)ap;
    f32x4 a1 = *(const f32x4*)(ap+4);
    bf16x8 a, b;
#pragma unroll
    for(int j=0;j<4;j++){ a[j] = (bf16)a0[j]; a[4+j] = (bf16)a1[j]; }
#pragma unroll
    for(int j=0;j<8;j++) b[j] = (bf16)bp[(size_t)j*ldb];
    acc = __builtin_amdgcn_mfma_f32_16x16x32_bf16(a, b, acc, 0, 0, 0);
    ap += 32; bp += (size_t)32*ldb;
  }
  return acc;
}

__device__ __forceinline__ f32x4 mm16f(const float* __restrict__ A, const float* __restrict__ B,
                                       int lda, int ldb, int K, int mr, int nc, int lane){
  return mm16r(A + (size_t)mr*lda, B, ldb, K, nc, lane);
}

// ---- prep: zero logits accumulator + transpose W1 [256][512] -> W1T [512][256].
// Replaces the old hipMemsetAsync dispatch.
__global__ __launch_bounds__(256) void k_prep0(const float* __restrict__ W1,
    float* __restrict__ W1T, float* __restrict__ out){
  int t = blockIdx.x*256 + threadIdx.x;   // grid 128 -> 32768 threads
  for(int i=t; i<BB*POI; i+=32768) out[i] = 0.f;
  for(int i=t; i<EMB*UNITS; i+=32768){
    int r = i >> 9, c = i & 511;          // W1[r][c]
    W1T[(size_t)c*EMB + r] = W1[i];       // coalesced read; scattered write absorbed by L2
  }
}

// ---- merged GRU GEMMs with inlined x1 gather.
// grid (96, 2, 2). y: 0 = x1@gruK (z=0: emb[x[b]] rows, z=1: query rows), 1 = h0@gruR. z: k-half.
__global__ __launch_bounds__(256) void k_gru(const int* __restrict__ x, const float* __restrict__ query,
    const float* __restrict__ emb, const float* __restrict__ h0,
    const float* __restrict__ gruK, const float* __restrict__ gruR,
    float* __restrict__ xmP, float* __restrict__ hmP){
  int lane = threadIdx.x & 63, w = threadIdx.x >> 6;
  int col = blockIdx.x*16 + (lane & 15);
  int z = blockIdx.z;
  int mr = w*16 + (lane & 15);              // batch row 0..63
  const float* arow;
  const float* B;
  float* C;
  if(blockIdx.y){
    arow = h0 + (size_t)mr*512 + z*256;
    B = gruR + (size_t)(z*256)*1536;
    C = hmP + (size_t)z*BB*1536;
  } else {
    arow = z ? (query + (size_t)mr*256) : (emb + (size_t)x[mr]*EMB);
    B = gruK + (size_t)(z*256)*1536;
    C = xmP + (size_t)z*BB*1536;
  }
  f32x4 acc = mm16r(arow, B, 1536, 256, col, lane);
  int rb = w*16 + (lane >> 4)*4;
#pragma unroll
  for(int r=0;r<4;r++) C[(size_t)(rb+r)*1536 + col] = acc[r];
}

// ---- GRU gates (keras reset_after=True, z/r/h); sums the 2 k-split slabs; catd copy folded in
__global__ void k_gates(const float* __restrict__ xmP, const float* __restrict__ hmP,
                        const float* __restrict__ bias, const float* __restrict__ h0,
                        const float* __restrict__ catd,
                        float* __restrict__ hn, float* __restrict__ outc, float* __restrict__ dout){
  int b = blockIdx.x, u = threadIdx.x;  // 512 thr
  const float* x0 = xmP + b*1536; const float* x1s = xmP + (size_t)BB*1536 + b*1536;
  const float* h0s = hmP + b*1536; const float* h1s = hmP + (size_t)BB*1536 + b*1536;
  float xz = x0[u]      + x1s[u]      + bias[u];
  float xg = x0[512+u]  + x1s[512+u]  + bias[512+u];
  float xh = x0[1024+u] + x1s[1024+u] + bias[1024+u];
  float hz = h0s[u]      + h1s[u]      + bias[1536+u];
  float hg = h0s[512+u]  + h1s[512+u]  + bias[2048+u];
  float hh = h0s[1024+u] + h1s[1024+u] + bias[2560+u];
  float z = rcp_(1.f + exp2_(-L2E*(xz+hz)));
  float r = rcp_(1.f + exp2_(-L2E*(xg+hg)));
  float ca = xh + r*hh;
  ca = fminf(fmaxf(ca, -15.f), 15.f);
  float e = exp2_(2.f*L2E*ca);
  float hc = (e - 1.f)*rcp_(e + 1.f);
  float h = h0[b*512+u];
  float v = z*h + (1.f - z)*hc;
  hn[b*512+u] = v;
  outc[b*KCAT + 256 + u] = v;
  outc[b*KCAT + 768 + u] = catd[(size_t)b*512 + u];                  // cat_dec_hidden
  dout[(size_t)POI*BB + (size_t)b*512 + u] = v;                       // state
  dout[(size_t)POI*BB + (size_t)BB*512 + (size_t)b*512 + u] = v;      // output_
}

// ---- Eq = exp2(clamp(2*log2e*(hn@W2 + b2))) : [64,512]. grid 32.
__global__ __launch_bounds__(256) void k_qproj(const float* __restrict__ hn, const float* __restrict__ W2,
                        const float* __restrict__ W2b, float* __restrict__ Eq){
  int lane = threadIdx.x & 63, w = threadIdx.x >> 6;
  int col = blockIdx.x*16 + (lane & 15);
  f32x4 acc = mm16f(hn, W2, UNITS, UNITS, UNITS, w*16 + (lane & 15), col, lane);
  float bn = W2b[col];
  int rb = w*16 + (lane >> 4)*4;
#pragma unroll
  for(int r=0;r<4;r++){
    float v = (acc[r] + bn)*(2.f*L2E);
    Eq[(rb+r)*UNITS + col] = exp2_(fminf(fmaxf(v, -40.f), 40.f));
  }
}

// ---- fused vproj+score, grid (157, NY): 32 poi rows x (512/NY)-u slice per block.
// stage 1: Ev slice via MFMA (B from pre-transposed W1T -> contiguous f32x4 loads),
//          stored TRANSPOSED in LDS: evsT[u][p] (f32x4 store, conflict-free read).
// Eq slice staged in LDS once (coalesced); stage 2 is pure LDS+VALU:
// sc_y[b][p] = sum_{u in slice} Vw[u]/(Ev[p][u]*Eq[b][u]+1), 4p x 2b per thread.
template<int NY>
__global__ __launch_bounds__(256, 4) void k_vscore(
    const float* __restrict__ emb, const float* __restrict__ W1T,
    const float* __restrict__ W1b, const float* __restrict__ Eq,
    const float* __restrict__ Vw, float* __restrict__ scS){
  constexpr int USL = 512/NY;          // u-slice width
  __shared__ float evsT[USL][36];      // [u_local][p_local 0..31] +4 pad
  __shared__ float qs[64][USL+4];      // [b][u_local]
  __shared__ float vws[USL];
  int t = threadIdx.x, lane = t & 63, w = t >> 6;
  int p0 = blockIdx.x*32, uh = blockIdx.y*USL;
  int q = lane >> 4;
  // ---- stage 1
#pragma unroll
  for(int i=0;i<USL/64;i++){
    int colL = (w + 4*i)*16 + (lane & 15);        // local u col
    float bn = W1b[uh + colL];
    const float* brow = W1T + (size_t)(uh+colL)*EMB + q*8;
#pragma unroll
    for(int pq=0;pq<2;pq++){
      int mr = p0 + pq*16 + (lane & 15); if(mr >= POI) mr = POI-1;  // tail clamp
      const float* ap = emb + (size_t)mr*EMB + q*8;
      const float* bp = brow;
      f32x4 acc = {0.f,0.f,0.f,0.f};
#pragma unroll 2
      for(int k0=0;k0<EMB;k0+=32){
        f32x4 a0 = *(const f32x4*)ap, a1 = *(const f32x4*)(ap+4);
        f32x4 b0 = *(const f32x4*)bp, b1 = *(const f32x4*)(bp+4);
        bf16x8 a, b;
#pragma unroll
        for(int j=0;j<4;j++){ a[j]=(bf16)a0[j]; a[4+j]=(bf16)a1[j];
                              b[j]=(bf16)b0[j]; b[4+j]=(bf16)b1[j]; }
        acc = __builtin_amdgcn_mfma_f32_16x16x32_bf16(a,b,acc,0,0,0);
        ap += 32; bp += 32;
      }
      f32x4 ev;
#pragma unroll
      for(int r=0;r<4;r++){
        float v = (acc[r] + bn)*(2.f*L2E);
        ev[r] = exp2_(fminf(fmaxf(v,-40.f),40.f));
      }
      *(f32x4*)&evsT[colL][pq*16 + q*4] = ev;     // transposed store: 4 consecutive p
    }
  }
  // ---- stage Eq slice + Vw slice into LDS
  constexpr int CG = USL/4;
  for(int i=t; i<64*CG; i+=256){
    int b = i/CG, cg = i - b*CG;
    *(f32x4*)&qs[b][cg*4] = *(const f32x4*)&Eq[b*UNITS + uh + cg*4];
  }
  if(t < USL) vws[t] = Vw[uh + t];
  __syncthreads();
  // ---- stage 2: 4p x 2b per thread, all operands in LDS
  int pg = t & 7, bg = t >> 3;                    // p-quad 0..7, b-pair 0..31
  const float* q0r = &qs[2*bg][0];
  const float* q1r = &qs[2*bg+1][0];
  f32x4 s0 = {0.f,0.f,0.f,0.f}, s1 = {0.f,0.f,0.f,0.f};
#pragma unroll 2
  for(int u4=0; u4<USL/4; ++u4){
    f32x4 q0 = *(const f32x4*)&q0r[u4*4];
    f32x4 q1 = *(const f32x4*)&q1r[u4*4];
    f32x4 wv = *(const f32x4*)&vws[u4*4];
#pragma unroll
    for(int j=0;j<4;j++){
      f32x4 ev = *(const f32x4*)&evsT[u4*4+j][4*pg];
#pragma unroll
      for(int e=0;e<4;e++){
        s0[e] += wv[j]*rcp_(ev[e]*q0[j] + 1.f);
        s1[e] += wv[j]*rcp_(ev[e]*q1[j] + 1.f);
      }
    }
  }
  float* srow = scS + (size_t)blockIdx.y*BB*SCLD + (size_t)(2*bg)*SCLD + p0 + 4*pg;
  int pA = p0 + 4*pg;
  if(pA + 3 < POI){
    *(f32x4*)srow = s0;
    *(f32x4*)(srow + SCLD) = s1;
  } else {
#pragma unroll
    for(int e=0;e<4;e++) if(pA+e < POI){ srow[e] = s0[e]; srow[SCLD+e] = s1[e]; }
  }
}

// ---- per-b: s = SW - 2*sum_y(sc_y); softmax; UNnormalized exp kept in slab0; iv[b] stored.
__global__ __launch_bounds__(512) void k_softmax(float* __restrict__ sc, const float* __restrict__ Vw,
                                                 float* __restrict__ outc, float* __restrict__ ivb,
                                                 int nslab){
  __shared__ float red[512];
  int b = blockIdx.x, t = threadIdx.x;
  if(t < 256) outc[b*KCAT + t] = 0.f;        // zero ctx accumulator region
  red[t] = Vw[t];
  __syncthreads();
  for(int o=256;o>0;o>>=1){ if(t<o) red[t]+=red[t+o]; __syncthreads(); }
  float SW = red[0]; __syncthreads();
  float* sA = sc + (size_t)b*SCLD;
  float mx = -3.4e38f;
  for(int p=t;p<POI;p+=512){
    float acc = sA[p];
    for(int y=1;y<nslab;y++) acc += sA[(size_t)y*BB*SCLD + p];
    float s = SW - 2.f*acc;
    sA[p] = s;
    mx = fmaxf(mx, s);
  }
  red[t] = mx; __syncthreads();
  for(int o=256;o>0;o>>=1){ if(t<o) red[t]=fmaxf(red[t],red[t+o]); __syncthreads(); }
  float M = red[0]; __syncthreads();
  float sum = 0.f;
  for(int p=t;p<POI;p+=512){
    float wv = exp2_((sA[p] - M)*L2E);
    sA[p] = wv;                                // unnormalized; k_ctx applies iv
    sum += wv;
  }
  red[t] = sum; __syncthreads();
  for(int o=256;o>0;o>>=1){ if(t<o) red[t]+=red[t+o]; __syncthreads(); }
  if(t == 0) ivb[b] = rcp_(red[0]);
  if(t < SCLD-POI) sA[POI + t] = 0.f;          // zero k-pad for ctx GEMM
}

// ---- context = wb[64,5024] @ emb[5000,256] (split-K x13, atomic), scaled by iv[b] -> outc[:,0:256]
__global__ __launch_bounds__(256) void k_ctx(const float* __restrict__ wb, const float* __restrict__ emb,
                                             const float* __restrict__ ivb, float* __restrict__ outc){
  int lane = threadIdx.x & 63, w = threadIdx.x >> 6;
  int n = blockIdx.x*16 + (lane & 15);       // n < 256
  int ky = blockIdx.y;                        // 13 splits of 384
  int kbeg = ky*384;
  int mr = w*16 + (lane & 15);
  f32x4 acc = mm16f(wb + kbeg, emb + (size_t)kbeg*EMB, SCLD, EMB, 384, mr, n, lane);
  if(ky == 12){                               // tail [4992,5024): wb pad=0, emb row clamped
    int q = lane >> 4;
    const float* ap = wb + (size_t)mr*SCLD + 4992 + q*8;
    bf16x8 a, bfr;
#pragma unroll
    for(int j=0;j<8;j++) a[j] = (bf16)ap[j];
#pragma unroll
    for(int j=0;j<8;j++){
      int k = 4992 + q*8 + j; int kc = k < POI ? k : POI-1;
      bfr[j] = (bf16)emb[(size_t)kc*EMB + n];
    }
    acc = __builtin_amdgcn_mfma_f32_16x16x32_bf16(a, bfr, acc, 0, 0, 0);
  }
  int rb = w*16 + (lane >> 4)*4;
#pragma unroll
  for(int r=0;r<4;r++) atomicAdd(&outc[(size_t)(rb+r)*KCAT + n], acc[r]*ivb[rb+r]);
}

// ---- logits: split-K x4, atomicAdd into zeroed d_out; bias folded into split 0. grid (313,4).
__global__ __launch_bounds__(256) void k_logits(const float* __restrict__ A, const float* __restrict__ Bw,
                        const float* __restrict__ fcb, float* __restrict__ out){
  int lane = threadIdx.x & 63, w = threadIdx.x >> 6;
  int n = blockIdx.x*16 + (lane & 15);
  int nc = n < POI ? n : POI-1;
  int ky = blockIdx.y, kbeg = ky*320;         // 4 x 320 = 1280
  f32x4 acc = mm16f(A + kbeg, Bw + (size_t)kbeg*POI, KCAT, POI, 320,
                    w*16 + (lane & 15), nc, lane);
  int rb = w*16 + (lane >> 4)*4;
  if(n < POI){
    float bn = (ky == 0) ? fcb[n] : 0.f;
#pragma unroll
    for(int r=0;r<4;r++) atomicAdd(&out[(size_t)(rb+r)*POI + n], acc[r] + bn);
  }
}

extern "C" void kernel_launch(void* const* d_in, const int* in_sizes, int n_in,
                              void* d_out, int out_size, void* d_ws, size_t ws_size,
                              hipStream_t stream){
  const int*   x     = (const int*)d_in[0];
  const float* query = (const float*)d_in[1];
  const float* emb   = (const float*)d_in[2];
  // d_in[3] A_hat unused by reference
  const float* h0    = (const float*)d_in[4];
  const float* catd  = (const float*)d_in[5];
  const float* gruK  = (const float*)d_in[6];
  const float* gruR  = (const float*)d_in[7];
  const float* gruB  = (const float*)d_in[8];
  const float* W1    = (const float*)d_in[9];
  const float* W1b   = (const float*)d_in[10];
  const float* W2    = (const float*)d_in[11];
  const float* W2b   = (const float*)d_in[12];
  const float* Vw    = (const float*)d_in[13];
  // d_in[14] V_b: softmax-invariant, dropped
  const float* fcw   = (const float*)d_in[15];
  const float* fcb   = (const float*)d_in[16];
  float* out = (float*)d_out;

  int nslab = (ws_size >= (size_t)16*1024*1024) ? 8 : 4;

  char* ws = (char*)d_ws;
  size_t off = 0;
  auto alloc = [&](size_t bytes)->void*{ void* p = ws + off; off += (bytes + 255) & ~(size_t)255; return p; };
  float* outc = (float*)alloc((size_t)BB*KCAT*4);
  float* xmP  = (float*)alloc((size_t)2*BB*1536*4);
  float* hmP  = (float*)alloc((size_t)2*BB*1536*4);
  float* hn   = (float*)alloc((size_t)BB*512*4);
  float* Eq   = (float*)alloc((size_t)BB*512*4);
  float* W1T  = (float*)alloc((size_t)UNITS*EMB*4);
  float* ivb  = (float*)alloc((size_t)BB*4);
  float* sc   = (float*)alloc((size_t)nslab*BB*SCLD*4);   // nslab u-slice slabs

  k_prep0  <<<128, 256, 0, stream>>>(W1, W1T, out);
  k_gru    <<<dim3(96,2,2), 256, 0, stream>>>(x, query, emb, h0, gruK, gruR, xmP, hmP);
  k_gates  <<<BB, 512, 0, stream>>>(xmP, hmP, gruB, h0, catd, hn, outc, out);
  k_qproj  <<<32, 256, 0, stream>>>(hn, W2, W2b, Eq);
  if(nslab == 8)
    k_vscore<8><<<dim3(157,8), 256, 0, stream>>>(emb, W1T, W1b, Eq, Vw, sc);
  else
    k_vscore<4><<<dim3(157,4), 256, 0, stream>>>(emb, W1T, W1b, Eq, Vw, sc);
  k_softmax<<<BB, 512, 0, stream>>>(sc, Vw, outc, ivb, nslab);
  k_ctx    <<<dim3(16,13), 256, 0, stream>>>(sc, emb, ivb, outc);
  k_logits <<<dim3(313,4), 256, 0, stream>>>(outc, fcw, fcb, out);
}

// Round 3
// 201.314 us; speedup vs baseline: 1.0861x; 1.0861x over previous
//
#include <hip/hip_runtime.h>
#include <hip/hip_bf16.h>

typedef __bf16 bf16;
typedef __bf16 bf16x8 __attribute__((ext_vector_type(8)));
typedef float f32x4 __attribute__((ext_vector_type(4)));

#define BB 64
#define EMB 256
#define UNITS 512
#define POI 5000
#define KCAT 1280
#define SCLD 5024   // sc row stride (5000 padded to x32)
#define L2E 1.4426950408889634f

__device__ __forceinline__ float rcp_(float x){ return __builtin_amdgcn_rcpf(x); }
__device__ __forceinline__ float exp2_(float x){ return __builtin_amdgcn_exp2f(x); }

__device__ __forceinline__ bf16x8 cvt8(f32x4 a0, f32x4 a1){
  bf16x8 o;
#pragma unroll
  for(int j=0;j<4;j++){ o[j]=(bf16)a0[j]; o[4+j]=(bf16)a1[j]; }
  return o;
}

// ---- fp32-A x fp32-B(strided) MFMA tile helper (kept for k_logits; B strided scalar).
__device__ __forceinline__ f32x4 mm16r(const float* __restrict__ ap, const float* __restrict__ B,
                                       int ldb, int K, int nc, int lane){
  int q = lane >> 4;
  f32x4 acc = {0.f,0.f,0.f,0.f};
  ap += q*8;
  const float* bp = B + (size_t)(q*8)*ldb + nc;
#pragma unroll 2
  for(int k0 = 0; k0 < K; k0 += 32){
    bf16x8 a = cvt8(*(const f32x4*)ap, *(const f32x4*)(ap+4));
    bf16x8 b;
#pragma unroll
    for(int j=0;j<8;j++) b[j] = (bf16)bp[(size_t)j*ldb];
    acc = __builtin_amdgcn_mfma_f32_16x16x32_bf16(a, b, acc, 0, 0, 0);
    ap += 32; bp += (size_t)32*ldb;
  }
  return acc;
}
__device__ __forceinline__ f32x4 mm16f(const float* __restrict__ A, const float* __restrict__ B,
                                       int lda, int ldb, int K, int mr, int nc, int lane){
  return mm16r(A + (size_t)mr*lda, B, ldb, K, nc, lane);
}

// ---- 64-row transpose tile: src fp32 [nRv][srcLd] rows [r0,r0+64) cols [c0,c0+cW)
//      -> dstT bf16 [*][dstLd] (dstT[c][r] = src[r][c]); rows >= nRv write 0 (pad fill).
__device__ __forceinline__ void t64(const float* __restrict__ src, int srcLd, int nRv,
    int r0, int c0, int cW, bf16* __restrict__ dstT, int dstLd, int dstRmax,
    int lane, int w){
  int r = r0 + lane;
  bool rv = r < nRv;
  int cw4 = cW >> 2;
  int cb = c0 + w*cw4;
  for(int c8=0;c8<cw4;c8+=8){
    int c = cb + c8;
    f32x4 v0={0.f,0.f,0.f,0.f}, v1={0.f,0.f,0.f,0.f};
    if(rv){ v0 = *(const f32x4*)(src + (size_t)r*srcLd + c);
            v1 = *(const f32x4*)(src + (size_t)r*srcLd + c + 4); }
    if(r < dstRmax){
#pragma unroll
      for(int j=0;j<4;j++){
        dstT[(size_t)(c+j)*dstLd + r]   = (bf16)v0[j];
        dstT[(size_t)(c+4+j)*dstLd + r] = (bf16)v1[j];
      }
    }
  }
}

// ---- prep: zero accumulators, bf16-pack emb, bf16-transpose W1/W2/gruK/gruR/emb, init mx/sum.
__global__ __launch_bounds__(256) void k_prep0(
    const float* __restrict__ emb, const float* __restrict__ W1, const float* __restrict__ W2,
    const float* __restrict__ gruK, const float* __restrict__ gruR,
    float* __restrict__ out, float* __restrict__ outc,
    bf16* __restrict__ embB, bf16* __restrict__ embTb,
    bf16* __restrict__ W1Tb, bf16* __restrict__ W2Tb,
    bf16* __restrict__ gruKTb, bf16* __restrict__ gruRTb,
    unsigned* __restrict__ mxb, float* __restrict__ sumb){
  int bx = blockIdx.x, t = threadIdx.x, lane = t & 63, w = t >> 6;
  if(bx < 80){                       // embB: rows [bx*64, +64), coalesced copy fp32->bf16
    int r0 = bx*64;
    for(int ch = t; ch < 2048; ch += 256){
      int r = r0 + (ch >> 5), cc = (ch & 31)*8;
      if(r < POI){
        f32x4 v0 = *(const f32x4*)(emb + (size_t)r*EMB + cc);
        f32x4 v1 = *(const f32x4*)(emb + (size_t)r*EMB + cc + 4);
        *(bf16x8*)(embB + (size_t)r*EMB + cc) = cvt8(v0, v1);
      }
    }
  } else if(bx < 240){               // embTb [256][5024]: 80 r-tiles x 2 c-halves
    int i = bx - 80;
    t64(emb, EMB, POI, (i>>1)*64, (i&1)*128, 128, embTb, SCLD, SCLD, lane, w);
  } else if(bx < 256){               // W2Tb [512][512]: 8 r-tiles x 2 c-halves
    int i = bx - 240;
    t64(W2, UNITS, UNITS, (i>>1)*64, (i&1)*256, 256, W2Tb, UNITS, UNITS, lane, w);
  } else if(bx < 264){               // W1Tb [512][256]: 4 r-tiles x 2 c-halves
    int i = bx - 256;
    t64(W1, UNITS, EMB, (i>>1)*64, (i&1)*256, 256, W1Tb, EMB, EMB, lane, w);
  } else if(bx < 328){               // gruKTb [1536][512]: 8 r-tiles x 8 c-eighths
    int i = bx - 264;
    t64(gruK, 1536, 512, (i>>3)*64, (i&7)*192, 192, gruKTb, 512, 512, lane, w);
  } else if(bx < 392){               // gruRTb
    int i = bx - 328;
    t64(gruR, 1536, 512, (i>>3)*64, (i&7)*192, 192, gruRTb, 512, 512, lane, w);
  } else if(bx < 432){               // zero logits accumulator (64x5000 f32 = 80000 f32x4)
    f32x4 z = {0.f,0.f,0.f,0.f};
    for(int i = (bx-392)*256 + t; i < 80000; i += 40*256) ((f32x4*)out)[i] = z;
  } else if(bx < 434){               // zero outc ctx region (64 x 256)
    f32x4 z = {0.f,0.f,0.f,0.f};
    for(int i = (bx-432)*256 + t; i < 4096; i += 512){
      int b = i >> 6, jj = i & 63;
      ((f32x4*)(outc + (size_t)b*KCAT))[jj] = z;
    }
  } else {                           // init atomic max/sum
    if(t < BB){ mxb[t] = 0u; sumb[t] = 0.f; }
  }
}

// ---- merged GRU GEMMs, bf16-transposed weights, x1 gather inlined.
// grid (96, 2, 2). y: 0 = x1@gruK (z=0: embB[x[b]], z=1: query), 1 = h0@gruR. z: k-half.
__global__ __launch_bounds__(256) void k_gru(const int* __restrict__ x, const float* __restrict__ query,
    const bf16* __restrict__ embB, const float* __restrict__ h0,
    const bf16* __restrict__ gruKTb, const bf16* __restrict__ gruRTb,
    float* __restrict__ xmP, float* __restrict__ hmP){
  int lane = threadIdx.x & 63, w = threadIdx.x >> 6;
  int col = blockIdx.x*16 + (lane & 15);
  int y = blockIdx.y, z = blockIdx.z;
  int mr = w*16 + (lane & 15);
  int q = lane >> 4;
  const bf16* bp = (y ? gruRTb : gruKTb) + (size_t)col*512 + z*256 + q*8;
  float* C = (y ? hmP : xmP) + (size_t)z*BB*1536;
  f32x4 acc = {0.f,0.f,0.f,0.f};
  if(y == 0 && z == 0){
    const bf16* ap = embB + (size_t)x[mr]*EMB + q*8;
#pragma unroll
    for(int k0=0;k0<256;k0+=32){
      bf16x8 a = *(const bf16x8*)ap, b = *(const bf16x8*)bp;
      acc = __builtin_amdgcn_mfma_f32_16x16x32_bf16(a,b,acc,0,0,0);
      ap += 32; bp += 32;
    }
  } else {
    const float* apf = y ? (h0 + (size_t)mr*512 + z*256 + q*8)
                         : (query + (size_t)mr*256 + q*8);
#pragma unroll
    for(int k0=0;k0<256;k0+=32){
      bf16x8 a = cvt8(*(const f32x4*)apf, *(const f32x4*)(apf+4));
      bf16x8 b = *(const bf16x8*)bp;
      acc = __builtin_amdgcn_mfma_f32_16x16x32_bf16(a,b,acc,0,0,0);
      apf += 32; bp += 32;
    }
  }
  int rb = w*16 + (lane >> 4)*4;
#pragma unroll
  for(int r=0;r<4;r++) C[(size_t)(rb+r)*1536 + col] = acc[r];
}

// ---- GRU gates; grid (64,2) x 256 thr; sums the 2 k-split slabs; catd copy folded in
__global__ __launch_bounds__(256) void k_gates(const float* __restrict__ xmP, const float* __restrict__ hmP,
                        const float* __restrict__ bias, const float* __restrict__ h0,
                        const float* __restrict__ catd,
                        float* __restrict__ hn, float* __restrict__ outc, float* __restrict__ dout){
  int b = blockIdx.x, u = blockIdx.y*256 + threadIdx.x;
  const float* x0 = xmP + b*1536; const float* x1s = xmP + (size_t)BB*1536 + b*1536;
  const float* h0s = hmP + b*1536; const float* h1s = hmP + (size_t)BB*1536 + b*1536;
  float xz = x0[u]      + x1s[u]      + bias[u];
  float xg = x0[512+u]  + x1s[512+u]  + bias[512+u];
  float xh = x0[1024+u] + x1s[1024+u] + bias[1024+u];
  float hz = h0s[u]      + h1s[u]      + bias[1536+u];
  float hg = h0s[512+u]  + h1s[512+u]  + bias[2048+u];
  float hh = h0s[1024+u] + h1s[1024+u] + bias[2560+u];
  float z = rcp_(1.f + exp2_(-L2E*(xz+hz)));
  float r = rcp_(1.f + exp2_(-L2E*(xg+hg)));
  float ca = xh + r*hh;
  ca = fminf(fmaxf(ca, -15.f), 15.f);
  float e = exp2_(2.f*L2E*ca);
  float hc = (e - 1.f)*rcp_(e + 1.f);
  float h = h0[b*512+u];
  float v = z*h + (1.f - z)*hc;
  hn[b*512+u] = v;
  outc[b*KCAT + 256 + u] = v;
  outc[b*KCAT + 768 + u] = catd[(size_t)b*512 + u];                  // cat_dec_hidden
  dout[(size_t)POI*BB + (size_t)b*512 + u] = v;                       // state
  dout[(size_t)POI*BB + (size_t)BB*512 + (size_t)b*512 + u] = v;      // output_
}

// ---- Eq = exp2(clamp(2*log2e*(hn@W2 + b2))): grid 128 blocks (4 r-tiles x 32 c-tiles),
//      4-way K-split across waves, LDS-atomic reduce.
__global__ __launch_bounds__(256) void k_qproj(const float* __restrict__ hn, const bf16* __restrict__ W2Tb,
                        const float* __restrict__ W2b, float* __restrict__ Eq){
  __shared__ float accs[16][17];
  int t = threadIdx.x, lane = t & 63, w = t >> 6;
  int c16 = blockIdx.x & 31, r16 = blockIdx.x >> 5;
  for(int i=t;i<16*17;i+=256) ((float*)accs)[i] = 0.f;
  __syncthreads();
  int q = lane >> 4;
  int mr  = r16*16 + (lane & 15);
  int col = c16*16 + (lane & 15);
  const float* ap = hn + (size_t)mr*UNITS + w*128 + q*8;
  const bf16*  bp = W2Tb + (size_t)col*UNITS + w*128 + q*8;
  f32x4 acc = {0.f,0.f,0.f,0.f};
#pragma unroll
  for(int k0=0;k0<128;k0+=32){
    bf16x8 a = cvt8(*(const f32x4*)ap, *(const f32x4*)(ap+4));
    bf16x8 b = *(const bf16x8*)bp;
    acc = __builtin_amdgcn_mfma_f32_16x16x32_bf16(a,b,acc,0,0,0);
    ap += 32; bp += 32;
  }
#pragma unroll
  for(int r=0;r<4;r++) atomicAdd(&accs[q*4+r][lane & 15], acc[r]);
  __syncthreads();
  int r = t >> 4, c = t & 15;
  int colg = c16*16 + c;
  float v = (accs[r][c] + W2b[colg])*(2.f*L2E);
  Eq[(size_t)(r16*16+r)*UNITS + colg] = exp2_(fminf(fmaxf(v,-40.f),40.f));
}

// ---- fused vproj+score, grid (313, NY): 16 poi rows x (512/NY)-u slice per block.
// stage 1: bf16 MFMA (embB x W1Tb, both contiguous 16B loads) -> evsT[u][p] in LDS.
// stage 2: thread = (p-quad, b): 1 global Eq f32x4 per 48 VALU, ev via 4-way LDS broadcast.
template<int NY>
__global__ __launch_bounds__(256, 8) void k_vscore(
    const bf16* __restrict__ embB, const bf16* __restrict__ W1Tb,
    const float* __restrict__ W1b, const float* __restrict__ Eq,
    const float* __restrict__ Vw, float* __restrict__ scS){
  constexpr int USL = 512/NY;
  __shared__ float evsT[USL][20];      // [u_local][p_local(16) + pad]
  __shared__ float vws[USL];
  int t = threadIdx.x, lane = t & 63, w = t >> 6;
  int p0 = blockIdx.x*16, uh = blockIdx.y*USL;
  int q = lane >> 4;
  // stage 1
  int mr = p0 + (lane & 15); if(mr > POI-1) mr = POI-1;
#pragma unroll
  for(int i=0;i<USL/64;i++){
    int colL = (w + 4*i)*16 + (lane & 15);
    const bf16* ap = embB + (size_t)mr*EMB + q*8;
    const bf16* bp = W1Tb + (size_t)(uh+colL)*EMB + q*8;
    f32x4 acc = {0.f,0.f,0.f,0.f};
#pragma unroll
    for(int k0=0;k0<EMB;k0+=32){
      bf16x8 a = *(const bf16x8*)ap, b = *(const bf16x8*)bp;
      acc = __builtin_amdgcn_mfma_f32_16x16x32_bf16(a,b,acc,0,0,0);
      ap += 32; bp += 32;
    }
    float bn = W1b[uh+colL];
    f32x4 ev;
#pragma unroll
    for(int r=0;r<4;r++){
      float v = (acc[r] + bn)*(2.f*L2E);
      ev[r] = exp2_(fminf(fmaxf(v,-40.f),40.f));
    }
    *(f32x4*)&evsT[colL][q*4] = ev;    // transposed: 4 consecutive p
  }
  if(t < USL) vws[t] = Vw[uh + t];
  __syncthreads();
  // stage 2: pg = p-quad (0..3), b = 0..63
  int pg = t & 3, b = t >> 2;
  const float* qrow = Eq + (size_t)b*UNITS + uh;
  f32x4 s = {0.f,0.f,0.f,0.f};
#pragma unroll 4
  for(int u4=0; u4<USL/4; ++u4){
    f32x4 q4 = *(const f32x4*)&qrow[u4*4];
    f32x4 wv = *(const f32x4*)&vws[u4*4];
#pragma unroll
    for(int j=0;j<4;j++){
      f32x4 ev = *(const f32x4*)&evsT[u4*4+j][4*pg];
#pragma unroll
      for(int e=0;e<4;e++)
        s[e] += wv[j]*rcp_(ev[e]*q4[j] + 1.f);
    }
  }
  int pA = p0 + 4*pg;
  float* srow = scS + (size_t)blockIdx.y*BB*SCLD + (size_t)b*SCLD + pA;
  if(pA + 3 < POI) *(f32x4*)srow = s;
  else {
#pragma unroll
    for(int e=0;e<4;e++) if(pA+e < POI) srow[e] = s[e];
  }
}

// ---- softmax pass A: combine slabs, s = -2*sum (SW const cancels in softmax), block max -> atomicMax
__global__ __launch_bounds__(256) void k_smax_a(float* __restrict__ sc, unsigned* __restrict__ mxb,
                                                int nslab){
  __shared__ float red[256];
  int b = blockIdx.x, y = blockIdx.y, t = threadIdx.x;
  float* sA = sc + (size_t)b*SCLD;
  int pend = (y+1)*640; if(pend > POI) pend = POI;
  float mx = -3.4e38f;
  for(int p = y*640 + t; p < pend; p += 256){
    float acc = sA[p];
    for(int s2=1;s2<nslab;s2++) acc += sA[(size_t)s2*BB*SCLD + p];
    float v = -2.f*acc;
    sA[p] = v;
    mx = fmaxf(mx, v);
  }
  red[t] = mx; __syncthreads();
  for(int o=128;o>0;o>>=1){ if(t<o) red[t]=fmaxf(red[t],red[t+o]); __syncthreads(); }
  if(t==0){
    unsigned u = __float_as_uint(red[0]);
    unsigned key = (u & 0x80000000u) ? ~u : (u | 0x80000000u);
    atomicMax(mxb + b, key);
  }
}

// ---- softmax pass B: e = exp2(s - M), block sum -> atomicAdd; zero k-pad
__global__ __launch_bounds__(256) void k_smax_b(float* __restrict__ sc, const unsigned* __restrict__ mxb,
                                                float* __restrict__ sumb){
  __shared__ float red[256];
  int b = blockIdx.x, y = blockIdx.y, t = threadIdx.x;
  unsigned key = mxb[b];
  unsigned uu = (key & 0x80000000u) ? (key ^ 0x80000000u) : ~key;
  float M = __uint_as_float(uu);
  float* sA = sc + (size_t)b*SCLD;
  int pend = (y+1)*640; if(pend > POI) pend = POI;
  float sm = 0.f;
  for(int p = y*640 + t; p < pend; p += 256){
    float e = exp2_((sA[p] - M)*L2E);
    sA[p] = e;                         // unnormalized; k_ctx applies 1/sum
    sm += e;
  }
  if(y == 7 && t < SCLD-POI) sA[POI + t] = 0.f;
  red[t] = sm; __syncthreads();
  for(int o=128;o>0;o>>=1){ if(t<o) red[t]+=red[t+o]; __syncthreads(); }
  if(t==0) atomicAdd(sumb + b, red[0]);
}

// ---- context = wb[64,5024] @ emb[5024,256] via embTb (bf16, contiguous), split-K x79, scaled 1/sum
__global__ __launch_bounds__(256) void k_ctx(const float* __restrict__ wb, const bf16* __restrict__ embTb,
                                             const float* __restrict__ sumb, float* __restrict__ outc){
  int lane = threadIdx.x & 63, w = threadIdx.x >> 6;
  int n = blockIdx.x*16 + (lane & 15);       // n < 256
  int ky = blockIdx.y;                        // 79 splits of 64 (last 32)
  int kbeg = ky*64;
  int K = (ky == 78) ? 32 : 64;
  int mr = w*16 + (lane & 15);
  int q = lane >> 4;
  const float* ap = wb + (size_t)mr*SCLD + kbeg + q*8;
  const bf16*  bp = embTb + (size_t)n*SCLD + kbeg + q*8;
  f32x4 acc = {0.f,0.f,0.f,0.f};
  for(int k0=0;k0<K;k0+=32){
    bf16x8 a = cvt8(*(const f32x4*)ap, *(const f32x4*)(ap+4));
    bf16x8 b = *(const bf16x8*)bp;
    acc = __builtin_amdgcn_mfma_f32_16x16x32_bf16(a,b,acc,0,0,0);
    ap += 32; bp += 32;
  }
  int rb = w*16 + (lane >> 4)*4;
#pragma unroll
  for(int r=0;r<4;r++) atomicAdd(&outc[(size_t)(rb+r)*KCAT + n], acc[r]*rcp_(sumb[rb+r]));
}

// ---- logits: split-K x8, atomicAdd into zeroed d_out; bias folded into split 0. grid (313,8).
__global__ __launch_bounds__(256) void k_logits(const float* __restrict__ A, const float* __restrict__ Bw,
                        const float* __restrict__ fcb, float* __restrict__ out){
  int lane = threadIdx.x & 63, w = threadIdx.x >> 6;
  int n = blockIdx.x*16 + (lane & 15);
  int nc = n < POI ? n : POI-1;
  int ky = blockIdx.y, kbeg = ky*160;         // 8 x 160 = 1280
  f32x4 acc = mm16f(A + kbeg, Bw + (size_t)kbeg*POI, KCAT, POI, 160,
                    w*16 + (lane & 15), nc, lane);
  int rb = w*16 + (lane >> 4)*4;
  if(n < POI){
    float bn = (ky == 0) ? fcb[n] : 0.f;
#pragma unroll
    for(int r=0;r<4;r++) atomicAdd(&out[(size_t)(rb+r)*POI + n], acc[r] + bn);
  }
}

extern "C" void kernel_launch(void* const* d_in, const int* in_sizes, int n_in,
                              void* d_out, int out_size, void* d_ws, size_t ws_size,
                              hipStream_t stream){
  const int*   x     = (const int*)d_in[0];
  const float* query = (const float*)d_in[1];
  const float* emb   = (const float*)d_in[2];
  // d_in[3] A_hat unused by reference
  const float* h0    = (const float*)d_in[4];
  const float* catd  = (const float*)d_in[5];
  const float* gruK  = (const float*)d_in[6];
  const float* gruR  = (const float*)d_in[7];
  const float* gruB  = (const float*)d_in[8];
  const float* W1    = (const float*)d_in[9];
  const float* W1b   = (const float*)d_in[10];
  const float* W2    = (const float*)d_in[11];
  const float* W2b   = (const float*)d_in[12];
  const float* Vw    = (const float*)d_in[13];
  // d_in[14] V_b: softmax-invariant, dropped
  const float* fcw   = (const float*)d_in[15];
  const float* fcb   = (const float*)d_in[16];
  float* out = (float*)d_out;

  int nslab = (ws_size >= (size_t)24*1024*1024) ? 8 : 4;

  char* ws = (char*)d_ws;
  size_t off = 0;
  auto alloc = [&](size_t bytes)->void*{ void* p = ws + off; off += (bytes + 255) & ~(size_t)255; return p; };
  float* outc   = (float*)alloc((size_t)BB*KCAT*4);
  float* xmP    = (float*)alloc((size_t)2*BB*1536*4);
  float* hmP    = (float*)alloc((size_t)2*BB*1536*4);
  float* hn     = (float*)alloc((size_t)BB*512*4);
  float* Eq     = (float*)alloc((size_t)BB*512*4);
  bf16*  embB   = (bf16*)alloc((size_t)POI*EMB*2);
  bf16*  embTb  = (bf16*)alloc((size_t)EMB*SCLD*2);
  bf16*  W1Tb   = (bf16*)alloc((size_t)UNITS*EMB*2);
  bf16*  W2Tb   = (bf16*)alloc((size_t)UNITS*UNITS*2);
  bf16*  gruKTb = (bf16*)alloc((size_t)1536*512*2);
  bf16*  gruRTb = (bf16*)alloc((size_t)1536*512*2);
  unsigned* mxb = (unsigned*)alloc((size_t)BB*4);
  float* sumb   = (float*)alloc((size_t)BB*4);
  float* sc     = (float*)alloc((size_t)nslab*BB*SCLD*4);

  k_prep0  <<<435, 256, 0, stream>>>(emb, W1, W2, gruK, gruR, out, outc,
                                     embB, embTb, W1Tb, W2Tb, gruKTb, gruRTb, mxb, sumb);
  k_gru    <<<dim3(96,2,2), 256, 0, stream>>>(x, query, embB, h0, gruKTb, gruRTb, xmP, hmP);
  k_gates  <<<dim3(BB,2), 256, 0, stream>>>(xmP, hmP, gruB, h0, catd, hn, outc, out);
  k_qproj  <<<128, 256, 0, stream>>>(hn, W2Tb, W2b, Eq);
  if(nslab == 8)
    k_vscore<8><<<dim3(313,8), 256, 0, stream>>>(embB, W1Tb, W1b, Eq, Vw, sc);
  else
    k_vscore<4><<<dim3(313,4), 256, 0, stream>>>(embB, W1Tb, W1b, Eq, Vw, sc);
  k_smax_a <<<dim3(BB,8), 256, 0, stream>>>(sc, mxb, nslab);
  k_smax_b <<<dim3(BB,8), 256, 0, stream>>>(sc, mxb, sumb);
  k_ctx    <<<dim3(16,79), 256, 0, stream>>>(sc, embTb, sumb, outc);
  k_logits <<<dim3(313,8), 256, 0, stream>>>(outc, fcw, fcb, out);
}